// Round 6
// baseline (401.248 us; speedup 1.0000x reference)
//
#include <hip/hip_runtime.h>

// Problem constants (fixed by reference setup_inputs)
constexpr int B  = 4;
constexpr int C  = 128;    // == Cv
constexpr int hw = 16384;  // h*w = 128*128
constexpr int W_ = 256;
constexpr int HW = 65536;  // H*W
constexpr int K  = 16;
constexpr int P_TILE = 16;                       // positions per block
constexpr int BLOCKS_PER_BATCH = hw / P_TILE;    // 1024

constexpr int CHUNK_N = 64;                      // n-positions per chunk
constexpr int CPB     = 16;                      // chunks per block
constexpr int CHUNKS_PER_BATCH_T = HW / CHUNK_N; // 1024

typedef __attribute__((ext_vector_type(8))) _Float16 half8;

__device__ __forceinline__ void async_copy16(const float* gsrc, float* ldst)
{
    // 16B per lane, LDS dest = wave-uniform base + lane*16 (linear).
    __builtin_amdgcn_global_load_lds(
        (const __attribute__((address_space(1))) void*)gsrc,
        (__attribute__((address_space(3))) void*)ldst,
        16, 0, 0);
}

// Transpose+convert: S,R fp32 (C,HW) -> interleaved fp16 KV (HW, 256) per batch.
// KV[n][c] = S[c][n] (c<128), R[c-128][n] (c>=128).
//
// MLP-uncapped staging: fp32 rows are DMA'd into LDS via global_load_lds
// (zero VGPR per outstanding load). Double-buffered 64KiB chunks with raw
// s_barrier + counted s_waitcnt vmcnt(16) (never 0 in the loop) keep the next
// chunk's 16 loads/wave in flight across the whole drain phase: bytes-in-flight
// per CU rises ~16x vs register staging, flipping the kernel from
// latency-bound (~3.4 TB/s demand, invariant across r2/r3/r5) to BW-bound.
//
// Swizzle (rule #21, both-sides-or-neither): LDS dest is LINEAR; the global
// SOURCE lane address is pre-swizzled (quad q = qs ^ ((ch>>3)&15)) and the
// drain read applies the same XOR -> drain banks spread to 16 banks x 4 lanes
// (~1.58x, acceptable). Drain converts fp32->fp16 and writes dense 512B
// records (32 lanes span one record, fully coalesced).
__global__ __launch_bounds__(256) void transpose_kv_f16(
    const float* __restrict__ S, const float* __restrict__ R,
    _Float16* __restrict__ KV)
{
    __shared__ float bufs[2][256 * CHUNK_N];     // 2 x 64 KiB
    const int tid  = threadIdx.x;                // 0..255
    const int lane = tid & 63;
    const int w64  = tid >> 6;                   // wave id 0..3
    const int u    = tid & 31;                   // drain: ch-group (8u..8u+7)
    const int rl   = tid >> 5;                   // drain: record sub-id 0..7

    auto STAGE = [&](float* buf, int g) {
        const int z  = g >> 10;                  // batch
        const int n0 = (g & 1023) << 6;          // n-offset
        const float* sB = S + (size_t)z * C * HW;
        const float* rB = R + (size_t)z * C * HW;
        #pragma unroll
        for (int j = 0; j < 16; ++j) {
            const int r0 = w64 * 64 + j * 4;     // first row of this instr
            const int ch = r0 + (lane >> 4);     // this lane's channel row
            const int qs = lane & 15;            // LDS quad slot (linear)
            const int q  = qs ^ ((ch >> 3) & 15);// pre-swizzled global quad
            const float* gp = ((ch < 128) ? sB + (size_t)ch * HW
                                          : rB + (size_t)(ch - 128) * HW)
                              + n0 + 4 * q;      // 256B span per row
            async_copy16(gp, buf + r0 * CHUNK_N);
        }
    };

    auto DRAIN = [&](const float* buf, int g) {
        const int z  = g >> 10;
        const int n0 = (g & 1023) << 6;
        _Float16* dbase = KV + (size_t)z * HW * 256;
        #pragma unroll
        for (int p = 0; p < 8; ++p) {
            const int n  = rl + 8 * p;           // 0..63
            const int nq = n >> 2;
            const int rm = n & 3;
            half8 hv;
            #pragma unroll
            for (int i = 0; i < 8; ++i) {
                const int ch = 8 * u + i;
                const int qs = nq ^ ((ch >> 3) & 15);
                hv[i] = (_Float16)buf[ch * CHUNK_N + qs * 4 + rm];
            }
            *reinterpret_cast<half8*>(
                &dbase[(size_t)(n0 + n) * 256 + 8 * u]) = hv;   // 512B/record
        }
    };

    const int g0 = blockIdx.x * CPB;

    STAGE(bufs[0], g0);
    for (int t = 0; t < CPB - 1; ++t) {
        STAGE(bufs[(t + 1) & 1], g0 + t + 1);    // next chunk: in flight below
        asm volatile("s_waitcnt vmcnt(16)" ::: "memory");  // chunk t landed
        __builtin_amdgcn_s_barrier();
        DRAIN(bufs[t & 1], g0 + t);
        __builtin_amdgcn_s_barrier();            // all done reading buf[t&1]
    }
    asm volatile("s_waitcnt vmcnt(0)" ::: "memory");
    __builtin_amdgcn_s_barrier();
    DRAIN(bufs[(CPB - 1) & 1], g0 + CPB - 1);
}

// Fused single-pass gather attention from interleaved fp16 KV rows.
// Per 16-lane group (one position p): for each of 16 gather rows, the group
// loads the full 512B K|V record cooperatively (2x16B per lane), computes the
// score via butterfly reduce, and online-softmax-accumulates V (flash-style
// running m, l). 8 rows (16 loads/lane) in flight to hide gather latency.
__global__ __launch_bounds__(256) void attn_gather_kv(
    const float* __restrict__ Q, const int* __restrict__ Pos,
    const _Float16* __restrict__ KV,
    float* __restrict__ outBuf, float* __restrict__ outM, int b0)
{
    __shared__ float q_s[P_TILE][132];   // Q tile, fp32, padded
    __shared__ float out_s[P_TILE][132];

    const int tid = threadIdx.x;
    const int bb  = blockIdx.x / BLOCKS_PER_BATCH;   // batch within this launch
    const int b   = b0 + bb;                         // absolute batch
    const int p0  = (blockIdx.x % BLOCKS_PER_BATCH) * P_TILE;

    // ---- stage Q tile (coalesced) ----
    for (int i = tid; i < P_TILE * C; i += 256) {
        int c = i >> 4, pl0 = i & 15;
        q_s[pl0][c] = Q[((size_t)(b * C + c)) * hw + p0 + pl0];
    }
    const int pl = tid >> 4;   // position in tile (= 16-lane group id)
    const int cg = tid & 15;   // lane within group
    const int p  = p0 + pl;
    int myidx;
    {
        const int rr = Pos[(((size_t)(b * 2 + 0) * hw) + p) * K + cg];   // coalesced
        const int cc = Pos[(((size_t)(b * 2 + 1) * hw) + p) * K + cg];
        myidx = rr * W_ + cc;
    }
    __syncthreads();

    float qf[8];
    #pragma unroll
    for (int i = 0; i < 8; ++i) qf[i] = q_s[pl][cg * 8 + i];

    float m = -1e30f, l = 0.f, myscore = 0.f;
    float acc[8];
    #pragma unroll
    for (int i = 0; i < 8; ++i) acc[i] = 0.f;

    const half8* base = reinterpret_cast<const half8*>(KV) + (size_t)bb * HW * 32;

    #pragma unroll
    for (int kc = 0; kc < K; kc += 8) {          // 8-row chunks: 16 loads in flight
        half8 kreg[8], vreg[8];
        #pragma unroll
        for (int r = 0; r < 8; ++r) {
            const int ridx = __shfl(myidx, kc + r, 16);    // group-uniform row idx
            const half8* row = base + (size_t)ridx * 32;   // 512B record, 512B aligned
            kreg[r] = row[cg];        // K halfs [cg*8, cg*8+8)
            vreg[r] = row[16 + cg];   // V halfs [cg*8, cg*8+8)
        }
        #pragma unroll
        for (int r = 0; r < 8; ++r) {
            float part = 0.f;
            #pragma unroll
            for (int i = 0; i < 8; ++i) part += qf[i] * (float)kreg[r][i];
            #pragma unroll
            for (int off = 1; off < 16; off <<= 1) part += __shfl_xor(part, off);
            // 'part' = score of row kc+r, identical across the 16-lane group
            const float mn    = fmaxf(m, part);
            const float scale = __expf(m - mn);      // ==1 when max unchanged; 0 on first row
            const float e     = __expf(part - mn);
            l = l * scale + e;
            #pragma unroll
            for (int i = 0; i < 8; ++i) acc[i] = acc[i] * scale + e * (float)vreg[r][i];
            m = mn;
            if (cg == kc + r) myscore = part;
        }
    }

    const float inv_l = 1.0f / l;
    const float attn  = __expf(myscore - m) * inv_l;   // == e_k / sum_k e_k
    outM[((size_t)b * hw + p) * K + cg] = attn;        // coalesced
    #pragma unroll
    for (int i = 0; i < 8; ++i) out_s[pl][cg * 8 + i] = acc[i] * inv_l;
    __syncthreads();
    for (int i = tid; i < P_TILE * C; i += 256) {
        int c = i >> 4, pl3 = i & 15;
        outBuf[((size_t)(b * C + c)) * hw + p0 + pl3] = out_s[pl3][c];   // coalesced
    }
}

// Fallback: direct gather from original (B,C,H,W) layout. Slow but needs no workspace.
__global__ __launch_bounds__(256) void attn_direct(
    const float* __restrict__ Q, const float* __restrict__ S, const float* __restrict__ R,
    const int* __restrict__ Pos, float* __restrict__ outBuf, float* __restrict__ outM)
{
    __shared__ float q_s[P_TILE][132];
    __shared__ float attn_s[P_TILE][17];
    __shared__ int   idx_s[P_TILE][K];
    __shared__ float out_s[P_TILE][132];

    const int tid = threadIdx.x;
    const int b   = blockIdx.x / BLOCKS_PER_BATCH;
    const int p0  = (blockIdx.x % BLOCKS_PER_BATCH) * P_TILE;

    for (int i = tid; i < P_TILE * C; i += 256) {
        int c = i >> 4, pl0 = i & 15;
        q_s[pl0][c] = Q[((size_t)(b * C + c)) * hw + p0 + pl0];
    }
    const int pl = tid >> 4;
    const int kk = tid & 15;
    const int p  = p0 + pl;
    const int rr = Pos[(((size_t)(b * 2 + 0) * hw) + p) * K + kk];
    const int cc = Pos[(((size_t)(b * 2 + 1) * hw) + p) * K + kk];
    const int idx = rr * W_ + cc;
    idx_s[pl][kk] = idx;
    __syncthreads();

    float score = 0.f;
    {
        const float* srow = S + (size_t)b * C * HW + idx;
        for (int c = 0; c < C; ++c) score += q_s[pl][c] * srow[(size_t)c * HW];
    }
    float mx = score;
    #pragma unroll
    for (int off = 1; off < 16; off <<= 1) mx = fmaxf(mx, __shfl_xor(mx, off));
    float e = __expf(score - mx);
    float ssum = e;
    #pragma unroll
    for (int off = 1; off < 16; off <<= 1) ssum += __shfl_xor(ssum, off);
    const float attn = e / ssum;
    outM[((size_t)b * hw + p) * K + kk] = attn;
    attn_s[pl][kk] = attn;
    __syncthreads();

    {
        const int pl2 = tid >> 4;
        const int cg  = tid & 15;
        float acc[8];
        #pragma unroll
        for (int i = 0; i < 8; ++i) acc[i] = 0.f;
        for (int k2 = 0; k2 < K; ++k2) {
            const float a = attn_s[pl2][k2];
            const float* rw = R + (size_t)b * C * HW + idx_s[pl2][k2];
            #pragma unroll
            for (int i = 0; i < 8; ++i) acc[i] += a * rw[(size_t)(cg * 8 + i) * HW];
        }
        #pragma unroll
        for (int i = 0; i < 8; ++i) out_s[pl2][cg * 8 + i] = acc[i];
    }
    __syncthreads();
    for (int i = tid; i < P_TILE * C; i += 256) {
        int c = i >> 4, pl3 = i & 15;
        outBuf[((size_t)(b * C + c)) * hw + p0 + pl3] = out_s[pl3][c];
    }
}

extern "C" void kernel_launch(void* const* d_in, const int* in_sizes, int n_in,
                              void* d_out, int out_size, void* d_ws, size_t ws_size,
                              hipStream_t stream)
{
    (void)in_sizes; (void)n_in; (void)out_size;
    const float* Q  = (const float*)d_in[0];
    const float* S  = (const float*)d_in[1];
    const float* R  = (const float*)d_in[2];
    const int*  Pos = (const int*)d_in[3];
    float* outBuf = (float*)d_out;
    float* outM   = outBuf + (size_t)B * C * hw;   // buffer is B*Cv*h*w elements

    const size_t fullBytes     = (size_t)B * HW * 256 * sizeof(_Float16);  // 128 MiB
    const size_t perBatchBytes = (size_t)HW * 256 * sizeof(_Float16);      // 32 MiB

    dim3 tb(256);
    if (ws_size >= fullBytes) {
        // convert+interleave all batches, then one fused compute launch.
        // 4096 chunks / 16 per block = 256 blocks = 1 block/CU (128 KiB LDS).
        _Float16* KVt = (_Float16*)d_ws;
        transpose_kv_f16<<<dim3(B * CHUNKS_PER_BATCH_T / CPB), tb, 0, stream>>>(
            S, R, KVt);
        attn_gather_kv<<<dim3(B * BLOCKS_PER_BATCH), 256, 0, stream>>>(
            Q, Pos, KVt, outBuf, outM, 0);
    } else if (ws_size >= perBatchBytes) {
        // per-batch convert + compute, workspace reused (1024 chunks / 16 = 64 blocks)
        _Float16* KVt = (_Float16*)d_ws;
        for (int b = 0; b < B; ++b) {
            transpose_kv_f16<<<dim3(CHUNKS_PER_BATCH_T / CPB), tb, 0, stream>>>(
                S + (size_t)b * C * HW, R + (size_t)b * C * HW, KVt);
            attn_gather_kv<<<dim3(BLOCKS_PER_BATCH), 256, 0, stream>>>(
                Q, Pos, KVt, outBuf, outM, b);
        }
    } else {
        // no usable workspace: direct (uncoalesced) fp32 gather
        attn_direct<<<dim3(B * BLOCKS_PER_BATCH), 256, 0, stream>>>(
            Q, S, R, Pos, outBuf, outM);
    }
}